// Round 9
// baseline (100.323 us; speedup 1.0000x reference)
//
#include <hip/hip_runtime.h>

// 2-layer tanh RNN, INP=6, HID=8, B=4096, T=512, + linear head to 1.
// R9: R8's fused both-layers step (16 lanes/element: lanes 0-7 h1, 8-15 h2;
// DPP-fused FMAs; head in lower lanes' dead wg[8..15] slots) x TWO
// independent batch elements per 16-lane group, interleaved in the
// instruction stream so each chain's dependency stalls are filled by the
// other chain's issue. 8 elements/wave, 512 waves.
// x staged via async global_load_lds, element-interleaved slot = q*8+e
// (conflict-free: element e -> bank 4e, same-address in-group = broadcast),
// double-buffered 64-step chunks, one counted vmcnt(0) per chunk.

#define INP 6
#define HID 8
#define TT  512
#define CH  64                // steps per chunk
#define NCH (TT/CH)           // 8 chunks
#define EPW 8                 // elements per wave (2 per 16-lane group)
#define CHF (CH*INP)          // 384 floats per element-chunk
#define BUFF (EPW*CHF)        // 3072 floats per LDS buffer

#define DPP_XOR1 0xB1   // quad_perm(1,0,3,2): lane ^ 1
#define DPP_XOR2 0x4E   // quad_perm(2,3,0,1): lane ^ 2
#define DPP_XOR3 0x1B   // quad_perm(3,2,1,0): lane ^ 3
#define DPP_HMIR 0x141  // row_half_mirror:    lane ^ 7  (within 16-row)
#define DPP_RMIR 0x140  // row_mirror:         lane ^ 15 (within 16-row)
#define DPP_ROR8 0x128  // row_ror:8:          lane ^ 8  (within 16-row)

template<int CTRL>
__device__ __forceinline__ float fdpp(float v) {
    return __int_as_float(__builtin_amdgcn_update_dpp(
        0, __float_as_int(v), CTRL, 0xF, 0xF, true));
}

// tanh(z) = 1 - 2/(exp2(z*2/ln2)+1); exact saturation at +/-inf
__device__ __forceinline__ float ftanh(float z) {
    float e = __builtin_amdgcn_exp2f(z * 2.885390082f);
    return fmaf(-2.0f, __builtin_amdgcn_rcpf(e + 1.0f), 1.0f);
}

// async global->LDS, 16B per lane, LDS dst = uniform base + lane*16
__device__ __forceinline__ void gl2lds16(const float* g, float* l) {
    __builtin_amdgcn_global_load_lds(
        (const __attribute__((address_space(1))) void*)g,
        (__attribute__((address_space(3))) void*)l, 16, 0, 0);
}

// read one timestep's 6 floats (3 x float2) from interleaved LDS layout:
// float f of element e lives at float offset 32*(f>>2) + 4*e + (f&3); BASE
// already includes the e*4 and buffer offset. F0 = t_local*6, even.
#define PF3(dst, base, F0) do {                                                            \
    dst[0] = *reinterpret_cast<const float2*>((base) + ((((F0)+0)>>2)<<5) + (((F0)+0)&3)); \
    dst[1] = *reinterpret_cast<const float2*>((base) + ((((F0)+2)>>2)<<5) + (((F0)+2)&3)); \
    dst[2] = *reinterpret_cast<const float2*>((base) + ((((F0)+4)>>2)<<5) + (((F0)+4)&3)); \
} while (0)

// one fused step for one chain. Entry: V = (h1(t) | h2(t-1)). Consumes
// x(t+1) in XC, prefetches into XN. Exit: V = (h1(t+1) | h2(t)). Captures
// head o(t-1) (= s in lower lanes) into OREG where j == (S+7)&7.
#define STEPX(S, V, OREG, XC, XN, PFBASE, PFF0, DOPF)              \
  {                                                                \
    if (DOPF) PF3(XN, PFBASE, PFF0);                               \
    float g7  = fdpp<DPP_HMIR>(V);                                 \
    float g8  = fdpp<DPP_ROR8>(V);                                 \
    float g15 = fdpp<DPP_RMIR>(V);                                 \
    float a0 = fmaf(wx0, XC[0].x, bias);                           \
    float a1 = wx1 * XC[0].y;                                      \
    float a2 = wx2 * XC[1].x;                                      \
    float a3 = wx3 * XC[1].y;                                      \
    a0 = fmaf(wx4, XC[2].x, a0);                                   \
    a1 = fmaf(wx5, XC[2].y, a1);                                   \
    a0 = fmaf(wg[0], V, a0);                                       \
    a1 = fmaf(wg[1], fdpp<DPP_XOR1>(V), a1);                       \
    a2 = fmaf(wg[2], fdpp<DPP_XOR2>(V), a2);                       \
    a3 = fmaf(wg[3], fdpp<DPP_XOR3>(V), a3);                       \
    a0 = fmaf(wg[4], fdpp<DPP_XOR3>(g7), a0);                      \
    a1 = fmaf(wg[5], fdpp<DPP_XOR2>(g7), a1);                      \
    a2 = fmaf(wg[6], fdpp<DPP_XOR1>(g7), a2);                      \
    a3 = fmaf(wg[7], g7, a3);                                      \
    float c0 = wg[8] * g8;                                         \
    float c1 = wg[9] * fdpp<DPP_XOR1>(g8);                         \
    c0 = fmaf(wg[10], fdpp<DPP_XOR2>(g8),  c0);                    \
    c1 = fmaf(wg[11], fdpp<DPP_XOR3>(g8),  c1);                    \
    c0 = fmaf(wg[12], fdpp<DPP_XOR3>(g15), c0);                    \
    c1 = fmaf(wg[13], fdpp<DPP_XOR2>(g15), c1);                    \
    c0 = fmaf(wg[14], fdpp<DPP_XOR1>(g15), c0);                    \
    c1 = fmaf(wg[15], g15, c1);                                    \
    float s   = c0 + c1;                                           \
    float pre = (a0 + a1) + (a2 + a3);                             \
    float tin = fmaf(upf, s, pre);                                 \
    V = ftanh(tin);                                                \
    OREG = (j == (((S) + 7) & 7)) ? s : OREG;                      \
  }

// both chains, interleaved at source level (same basic block -> the list
// scheduler fills chain-0 stalls with chain-1 issue and vice versa)
#define STEP2(S, XC0, XN0, RP0, XC1, XN1, RP1, PFF0, DOPF)  \
    STEPX(S, v0, oreg0, XC0, XN0, RP0, PFF0, DOPF)          \
    STEPX(S, v1, oreg1, XC1, XN1, RP1, PFF0, DOPF)

__global__ __launch_bounds__(64) void rnn_fused(
    const float* __restrict__ x,
    const float* __restrict__ Wih0, const float* __restrict__ Whh0,
    const float* __restrict__ bih0, const float* __restrict__ bhh0,
    const float* __restrict__ Wih1, const float* __restrict__ Whh1,
    const float* __restrict__ bih1, const float* __restrict__ bhh1,
    const float* __restrict__ Wout, const float* __restrict__ bout,
    float* __restrict__ out)
{
    __shared__ float lx[2 * BUFF];   // 24 KiB, double-buffered x chunks

    const int lane = threadIdx.x;        // 0..63
    const int j    = lane & 7;           // hidden unit owned by this lane
    const int up   = (lane >> 3) & 1;    // 0: h1 row, 1: h2 row
    const int eA   = (lane >> 4) * 2;    // group's chain-0 element slot
    const int ew0  = blockIdx.x * EPW;   // wave's first batch element

    // per-lane fused weights (shared by both chains):
    //  lower: m<8 -> Whh0 (gathers h1); m>=8 -> Wout[j^m] (head on h2(t-1))
    //  upper: m<8 -> Whh1 (gathers h2); m>=8 -> Wih1 (gathers h1)
    float wg[16];
#pragma unroll
    for (int M = 0; M < 8; ++M)
        wg[M] = up ? Whh1[j * HID + (j ^ M)] : Whh0[j * HID + (j ^ M)];
#pragma unroll
    for (int M = 8; M < 16; ++M)
        wg[M] = up ? Wih1[j * HID + (j ^ (M & 7))] : Wout[j ^ (M & 7)];
    const float wx0 = up ? 0.0f : Wih0[j * INP + 0];
    const float wx1 = up ? 0.0f : Wih0[j * INP + 1];
    const float wx2 = up ? 0.0f : Wih0[j * INP + 2];
    const float wx3 = up ? 0.0f : Wih0[j * INP + 3];
    const float wx4 = up ? 0.0f : Wih0[j * INP + 4];
    const float wx5 = up ? 0.0f : Wih0[j * INP + 5];
    const float bias = up ? (bih1[j] + bhh1[j]) : (bih0[j] + bhh0[j]);
    const float upf  = up ? 1.0f : 0.0f;
    const float bo   = bout[0];

    const float* xw = x + (size_t)ew0 * (TT * INP);
    float* ob0 = out + (size_t)(ew0 + eA) * TT;
    float* ob1 = ob0 + TT;

    // stage chunk c1 (8 elements x 384 floats) into buffer pn, interleaved:
    // LDS f4 slot S = q*8 + e  (e = element, q = f4 index within element)
    auto stage = [&](int c1, int pn) {
#pragma unroll
        for (int i = 0; i < 12; ++i) {
            const int e = lane & 7;
            const int q = i * 8 + (lane >> 3);
            const float* src = xw + (size_t)e * (TT * INP) + c1 * CHF + q * 4;
            gl2lds16(src, &lx[pn * BUFF + i * 256]);
        }
    };

    float v0 = 0.0f, v1 = 0.0f;      // (h1(t) | h2(t-1)) per chain
    float oreg0 = 0.0f, oreg1 = 0.0f;
    float2 xe0[3], xo0[3];           // chain-0 x regs: even t, odd t
    float2 xe1[3], xo1[3];           // chain-1 x regs

    // ---- prologue: stage chunk 0; v = (up ? 0 : h1(0)); prime odd=x(1) ----
    stage(0, 0);
    asm volatile("s_waitcnt vmcnt(0)" ::: "memory");
    __builtin_amdgcn_sched_barrier(0);
    {
        const float* rb0 = &lx[eA * 4];
        const float* rb1 = rb0 + 4;
        float2 t0[3], t1[3];
        PF3(t0, rb0, 0);  PF3(xo0, rb0, 6);
        PF3(t1, rb1, 0);  PF3(xo1, rb1, 6);
        float a = fmaf(wx0, t0[0].x, bias);
        a = fmaf(wx1, t0[0].y, a);  a = fmaf(wx2, t0[1].x, a);
        a = fmaf(wx3, t0[1].y, a);  a = fmaf(wx4, t0[2].x, a);
        a = fmaf(wx5, t0[2].y, a);
        v0 = up ? 0.0f : ftanh(a);
        float b = fmaf(wx0, t1[0].x, bias);
        b = fmaf(wx1, t1[0].y, b);  b = fmaf(wx2, t1[1].x, b);
        b = fmaf(wx3, t1[1].y, b);  b = fmaf(wx4, t1[2].x, b);
        b = fmaf(wx5, t1[2].y, b);
        v1 = up ? 0.0f : ftanh(b);
    }

    for (int c = 0; c < NCH; ++c) {
        const int p = c & 1;
        if (c < NCH - 1) stage(c + 1, p ^ 1);          // ~64 steps of cover
        const float* rb0 = &lx[p * BUFF + eA * 4];
        const float* rb1 = rb0 + 4;
        const float* nb0 = &lx[(p ^ 1) * BUFF + eA * 4];
        const float* nb1 = nb0 + 4;

        for (int sb = 0; sb < 7; ++sb) {
            const float* rp0 = rb0 + sb * 384;         // body base (48 f/el)
            const float* rp1 = rb1 + sb * 384;
            STEP2(0, xo0, xe0, rp0, xo1, xe1, rp1, 12, true)
            // slot 7 completed the previous 8-step block; store it
            if ((c | sb) && !up) {
                ob0[c * CH + sb * 8 - 8 + j] = oreg0 + bo;
                ob1[c * CH + sb * 8 - 8 + j] = oreg1 + bo;
            }
            STEP2(1, xe0, xo0, rp0, xe1, xo1, rp1, 18, true)
            STEP2(2, xo0, xe0, rp0, xo1, xe1, rp1, 24, true)
            STEP2(3, xe0, xo0, rp0, xe1, xo1, rp1, 30, true)
            STEP2(4, xo0, xe0, rp0, xo1, xe1, rp1, 36, true)
            STEP2(5, xe0, xo0, rp0, xe1, xo1, rp1, 42, true)
            STEP2(6, xo0, xe0, rp0, xo1, xe1, rp1, 48, true)
            STEP2(7, xe0, xo0, rp0, xe1, xo1, rp1, 54, true)
        }
        {   // body 7: steps 56..63, crossover into next chunk's buffer
            const float* rp0 = rb0 + 7 * 384;
            const float* rp1 = rb1 + 7 * 384;
            STEP2(0, xo0, xe0, rp0, xo1, xe1, rp1, 12, true)
            if (!up) {
                ob0[c * CH + 48 + j] = oreg0 + bo;     // block sb=6
                ob1[c * CH + 48 + j] = oreg1 + bo;
            }
            STEP2(1, xe0, xo0, rp0, xe1, xo1, rp1, 18, true)
            STEP2(2, xo0, xe0, rp0, xo1, xe1, rp1, 24, true)
            STEP2(3, xe0, xo0, rp0, xe1, xo1, rp1, 30, true)
            STEP2(4, xo0, xe0, rp0, xo1, xe1, rp1, 36, true)
            STEP2(5, xe0, xo0, rp0, xe1, xo1, rp1, 42, true)
            if (c < NCH - 1) {
                // next chunk staged long ago; one counted drain per 64 steps
                asm volatile("s_waitcnt vmcnt(0)" ::: "memory");
                __builtin_amdgcn_sched_barrier(0);
                STEP2(6, xo0, xe0, nb0, xo1, xe1, nb1, 0, true)  // x(next 0)
                STEP2(7, xe0, xo0, nb0, xe1, xo1, nb1, 6, true)  // x(next 1)
            } else {
                // last chunk: x(512) doesn't exist
                STEP2(6, xo0, xe0, rp0, xo1, xe1, rp1, 0, false)
                STEP2(7, xe0, xo0, rp0, xe1, xo1, rp1, 0, false)
            }
        }
    }

    // ---- epilogue: head for t = 511 (slot 7), then store final block ----
    {
        float g8  = fdpp<DPP_ROR8>(v0);
        float g15 = fdpp<DPP_RMIR>(v0);
        float c0 = wg[8] * g8;
        float c1 = wg[9] * fdpp<DPP_XOR1>(g8);
        c0 = fmaf(wg[10], fdpp<DPP_XOR2>(g8),  c0);
        c1 = fmaf(wg[11], fdpp<DPP_XOR3>(g8),  c1);
        c0 = fmaf(wg[12], fdpp<DPP_XOR3>(g15), c0);
        c1 = fmaf(wg[13], fdpp<DPP_XOR2>(g15), c1);
        c0 = fmaf(wg[14], fdpp<DPP_XOR1>(g15), c0);
        c1 = fmaf(wg[15], g15, c1);
        float s0 = c0 + c1;
        float h8  = fdpp<DPP_ROR8>(v1);
        float h15 = fdpp<DPP_RMIR>(v1);
        float d0 = wg[8] * h8;
        float d1 = wg[9] * fdpp<DPP_XOR1>(h8);
        d0 = fmaf(wg[10], fdpp<DPP_XOR2>(h8),  d0);
        d1 = fmaf(wg[11], fdpp<DPP_XOR3>(h8),  d1);
        d0 = fmaf(wg[12], fdpp<DPP_XOR3>(h15), d0);
        d1 = fmaf(wg[13], fdpp<DPP_XOR2>(h15), d1);
        d0 = fmaf(wg[14], fdpp<DPP_XOR1>(h15), d0);
        d1 = fmaf(wg[15], h15, d1);
        float s1 = d0 + d1;
        oreg0 = (j == 7) ? s0 : oreg0;
        oreg1 = (j == 7) ? s1 : oreg1;
        if (!up) {
            ob0[TT - 8 + j] = oreg0 + bo;
            ob1[TT - 8 + j] = oreg1 + bo;
        }
    }
}

extern "C" void kernel_launch(void* const* d_in, const int* in_sizes, int n_in,
                              void* d_out, int out_size, void* d_ws, size_t ws_size,
                              hipStream_t stream) {
    const float* x    = (const float*)d_in[0];
    const float* Wih0 = (const float*)d_in[1];
    const float* Whh0 = (const float*)d_in[2];
    const float* bih0 = (const float*)d_in[3];
    const float* bhh0 = (const float*)d_in[4];
    const float* Wih1 = (const float*)d_in[5];
    const float* Whh1 = (const float*)d_in[6];
    const float* bih1 = (const float*)d_in[7];
    const float* bhh1 = (const float*)d_in[8];
    const float* Wout = (const float*)d_in[9];
    const float* bout = (const float*)d_in[10];
    float* out = (float*)d_out;
    (void)d_ws; (void)ws_size; (void)in_sizes; (void)n_in; (void)out_size;

    // 4096 elements / 8 per wave = 512 single-wave blocks
    rnn_fused<<<512, 64, 0, stream>>>(x, Wih0, Whh0, bih0, bhh0,
                                      Wih1, Whh1, bih1, bhh1,
                                      Wout, bout, out);
}

// Round 10
// 62.104 us; speedup vs baseline: 1.6154x; 1.6154x over previous
//
#include <hip/hip_runtime.h>

// 2-layer tanh RNN, INP=6, HID=8, B=4096, T=512, + linear head to 1.
// R10 = R8 (best: 64.5us, fused both-layers step, 16 lanes/element,
// DPP-fused FMAs, head in lower lanes' dead slots) plus:
//  (1) distance-2 x prefetch: xP/xQ each hold TWO timesteps; even steps
//      issue the pair consumed two steps later -> ds_read latency fully
//      covered, no per-step lgkmcnt stall.
//  (2) tanh-path weights/biases pre-scaled by 2/ln2 at setup, so ftanh is
//      exp2(z) directly (multiply removed from the serial chain). Head
//      weights (Wout, lower lanes) stay unscaled; upf=0 keeps them out of
//      the tanh input there.

#define INP 6
#define HID 8
#define TT  512
#define CH  64                // steps per chunk
#define NCH (TT/CH)           // 8 chunks
#define EPW 4                 // elements per wave
#define CHF (CH*INP)          // 384 floats per element-chunk
#define BUFF (EPW*CHF)        // 1536 floats per LDS buffer

#define DPP_XOR1 0xB1   // quad_perm(1,0,3,2): lane ^ 1
#define DPP_XOR2 0x4E   // quad_perm(2,3,0,1): lane ^ 2
#define DPP_XOR3 0x1B   // quad_perm(3,2,1,0): lane ^ 3
#define DPP_HMIR 0x141  // row_half_mirror:    lane ^ 7  (within 16-row)
#define DPP_RMIR 0x140  // row_mirror:         lane ^ 15 (within 16-row)
#define DPP_ROR8 0x128  // row_ror:8:          lane ^ 8  (within 16-row)

#define KSC 2.88539008177793f   // 2 / ln(2)

template<int CTRL>
__device__ __forceinline__ float fdpp(float v) {
    return __int_as_float(__builtin_amdgcn_update_dpp(
        0, __float_as_int(v), CTRL, 0xF, 0xF, true));
}

// tanh on PRE-SCALED input: z already multiplied by 2/ln2.
// tanh = 1 - 2/(exp2(z)+1); exact saturation at +/-inf.
__device__ __forceinline__ float ftanhs(float z) {
    float e = __builtin_amdgcn_exp2f(z);
    return fmaf(-2.0f, __builtin_amdgcn_rcpf(e + 1.0f), 1.0f);
}

// async global->LDS, 16B per lane, LDS dst = uniform base + lane*16
__device__ __forceinline__ void gl2lds16(const float* g, float* l) {
    __builtin_amdgcn_global_load_lds(
        (const __attribute__((address_space(1))) void*)g,
        (__attribute__((address_space(3))) void*)l, 16, 0, 0);
}

// read one timestep's 6 floats (3 x float2) from interleaved LDS layout:
// float f of element el lives at float offset 16*(f>>2) + 4*el + (f&3);
// BASE already includes el*4 and buffer offset. F0 = t_local*6 (even).
#define PF3(dst, base, F0) do {                                                            \
    dst[0] = *reinterpret_cast<const float2*>((base) + ((((F0)+0)>>2)<<4) + (((F0)+0)&3)); \
    dst[1] = *reinterpret_cast<const float2*>((base) + ((((F0)+2)>>2)<<4) + (((F0)+2)&3)); \
    dst[2] = *reinterpret_cast<const float2*>((base) + ((((F0)+4)>>2)<<4) + (((F0)+4)&3)); \
} while (0)

// core fused step. Entry: v = (h1(t) | h2(t-1)). Consumes x(t+1) in XC.
// Exit: v = (h1(t+1) | h2(t)). Captures head o(t-1) (= s in lower lanes,
// from gathered h2(t-1)) into oreg where j == (S+7)&7.
#define STEPC(S, XC)                                               \
  {                                                                \
    float g7  = fdpp<DPP_HMIR>(v);                                 \
    float g8  = fdpp<DPP_ROR8>(v);                                 \
    float g15 = fdpp<DPP_RMIR>(v);                                 \
    float a0 = fmaf(wx0, XC[0].x, bias);                           \
    float a1 = wx1 * XC[0].y;                                      \
    a0 = fmaf(wx2, XC[1].x, a0);                                   \
    a1 = fmaf(wx3, XC[1].y, a1);                                   \
    a0 = fmaf(wx4, XC[2].x, a0);                                   \
    a1 = fmaf(wx5, XC[2].y, a1);                                   \
    a0 = fmaf(wg[0], v, a0);                                       \
    a1 = fmaf(wg[1], fdpp<DPP_XOR1>(v), a1);                       \
    a0 = fmaf(wg[2], fdpp<DPP_XOR2>(v), a0);                       \
    a1 = fmaf(wg[3], fdpp<DPP_XOR3>(v), a1);                       \
    a0 = fmaf(wg[4], fdpp<DPP_XOR3>(g7), a0);                      \
    a1 = fmaf(wg[5], fdpp<DPP_XOR2>(g7), a1);                      \
    a0 = fmaf(wg[6], fdpp<DPP_XOR1>(g7), a0);                      \
    a1 = fmaf(wg[7], g7, a1);                                      \
    float c0 = wg[8] * g8;                                         \
    float c1 = wg[9] * fdpp<DPP_XOR1>(g8);                         \
    c0 = fmaf(wg[10], fdpp<DPP_XOR2>(g8),  c0);                    \
    c1 = fmaf(wg[11], fdpp<DPP_XOR3>(g8),  c1);                    \
    c0 = fmaf(wg[12], fdpp<DPP_XOR3>(g15), c0);                    \
    c1 = fmaf(wg[13], fdpp<DPP_XOR2>(g15), c1);                    \
    c0 = fmaf(wg[14], fdpp<DPP_XOR1>(g15), c0);                    \
    c1 = fmaf(wg[15], g15, c1);                                    \
    float s   = c0 + c1;                                           \
    float pre = a0 + a1;                                           \
    float tin = fmaf(upf, s, pre);                                 \
    v = ftanhs(tin);                                               \
    oreg = (j == (((S) + 7) & 7)) ? s : oreg;                      \
  }

// even step: issue the pair consumed two steps later, then compute
#define STEPE(S, CURB, NXTB, PB1, F1, PB2, F2, DO1, DO2)  \
  {                                                       \
    if (DO1) PF3(NXTB[0], PB1, F1);                       \
    if (DO2) PF3(NXTB[1], PB2, F2);                       \
    STEPC(S, CURB[0])                                     \
  }
// odd step: pure compute
#define STEPO(S, CURB) { STEPC(S, CURB[1]) }

__global__ __launch_bounds__(64) void rnn_fused(
    const float* __restrict__ x,
    const float* __restrict__ Wih0, const float* __restrict__ Whh0,
    const float* __restrict__ bih0, const float* __restrict__ bhh0,
    const float* __restrict__ Wih1, const float* __restrict__ Whh1,
    const float* __restrict__ bih1, const float* __restrict__ bhh1,
    const float* __restrict__ Wout, const float* __restrict__ bout,
    float* __restrict__ out)
{
    __shared__ float lx[2 * BUFF];   // 12 KiB, double-buffered x chunks

    const int lane = threadIdx.x;        // 0..63
    const int j    = lane & 7;           // hidden unit owned by this lane
    const int up   = (lane >> 3) & 1;    // 0: h1 row, 1: h2 row
    const int el   = lane >> 4;          // element slot (0..3)
    const int ew0  = blockIdx.x * EPW;   // wave's first batch element

    // per-lane fused weights, tanh-path entries PRE-SCALED by 2/ln2:
    //  lower: m<8 -> K*Whh0 (gathers h1); m>=8 -> Wout[j^m] (head, UNscaled)
    //  upper: m<8 -> K*Whh1 (gathers h2); m>=8 -> K*Wih1 (gathers h1)
    float wg[16];
#pragma unroll
    for (int M = 0; M < 8; ++M)
        wg[M] = KSC * (up ? Whh1[j * HID + (j ^ M)] : Whh0[j * HID + (j ^ M)]);
#pragma unroll
    for (int M = 8; M < 16; ++M)
        wg[M] = up ? KSC * Wih1[j * HID + (j ^ (M & 7))] : Wout[j ^ (M & 7)];
    const float wx0 = up ? 0.0f : KSC * Wih0[j * INP + 0];
    const float wx1 = up ? 0.0f : KSC * Wih0[j * INP + 1];
    const float wx2 = up ? 0.0f : KSC * Wih0[j * INP + 2];
    const float wx3 = up ? 0.0f : KSC * Wih0[j * INP + 3];
    const float wx4 = up ? 0.0f : KSC * Wih0[j * INP + 4];
    const float wx5 = up ? 0.0f : KSC * Wih0[j * INP + 5];
    const float bias = KSC * (up ? (bih1[j] + bhh1[j]) : (bih0[j] + bhh0[j]));
    const float upf  = up ? 1.0f : 0.0f;
    const float bo   = bout[0];

    const float* xw = x + (size_t)ew0 * (TT * INP);
    float* ob = out + (size_t)(ew0 + el) * TT;

    // stage chunk c1 (4 elements x 384 floats) into buffer pn, interleaved:
    // LDS f4 slot S = q*4 + e  (e = element, q = f4 index within element)
    auto stage = [&](int c1, int pn) {
#pragma unroll
        for (int i = 0; i < 6; ++i) {
            const int e = lane & 3;
            const int q = i * 16 + (lane >> 2);
            const float* src = xw + (size_t)e * (TT * INP) + c1 * CHF + q * 4;
            gl2lds16(src, &lx[pn * BUFF + i * 256]);
        }
    };

    float v = 0.0f;           // lanes 0-7: h1(t); lanes 8-15: h2(t-1)
    float oreg = 0.0f;        // lower lanes: head outputs, slot = j
    float2 xP[2][3], xQ[2][3];   // pair buffers: 2 timesteps each

    // ---- prologue: stage chunk 0; h1(0); prime xP = [x(1), x(2)] ----
    stage(0, 0);
    asm volatile("s_waitcnt vmcnt(0)" ::: "memory");
    __builtin_amdgcn_sched_barrier(0);
    {
        const float* rb = &lx[el * 4];
        float2 x0[3];
        PF3(x0, rb, 0);        // x(0)
        PF3(xP[0], rb, 6);     // x(1)
        PF3(xP[1], rb, 12);    // x(2)
        float a = fmaf(wx0, x0[0].x, bias);
        a = fmaf(wx1, x0[0].y, a);
        a = fmaf(wx2, x0[1].x, a);
        a = fmaf(wx3, x0[1].y, a);
        a = fmaf(wx4, x0[2].x, a);
        a = fmaf(wx5, x0[2].y, a);
        float t0v = ftanhs(a);
        v = up ? 0.0f : t0v;   // h2(-1) = 0
    }

    for (int c = 0; c < NCH; ++c) {
        const int p = c & 1;
        if (c < NCH - 1) stage(c + 1, p ^ 1);          // ~64 steps of cover
        const float* rb = &lx[p * BUFF + el * 4];
        const float* nb = &lx[(p ^ 1) * BUFF + el * 4];

        for (int sb = 0; sb < 7; ++sb) {
            const float* rp = rb + sb * 192;           // body base
            STEPE(0, xP, xQ, rp, 18, rp, 24, true, true)
            // slot 7 completed the previous 8-step block; store it
            if ((c | sb) && !up) ob[c * CH + sb * 8 - 8 + j] = oreg + bo;
            STEPO(1, xP)
            STEPE(2, xQ, xP, rp, 30, rp, 36, true, true)
            STEPO(3, xQ)
            STEPE(4, xP, xQ, rp, 42, rp, 48, true, true)
            STEPO(5, xP)
            STEPE(6, xQ, xP, rp, 54, rp, 60, true, true)
            STEPO(7, xQ)
        }
        {   // body 7: steps 56..63, crossover into next chunk's buffer
            const float* rp = rb + 7 * 192;
            STEPE(0, xP, xQ, rp, 18, rp, 24, true, true)   // local 59,60
            if (!up) ob[c * CH + 48 + j] = oreg + bo;      // block sb=6
            STEPO(1, xP)
            STEPE(2, xQ, xP, rp, 30, rp, 36, true, true)   // local 61,62
            STEPO(3, xQ)
            if (c < NCH - 1) {
                // next chunk staged ~56 steps ago; drain once per chunk
                asm volatile("s_waitcnt vmcnt(0)" ::: "memory");
                __builtin_amdgcn_sched_barrier(0);
                STEPE(4, xP, xQ, rp, 42, nb, 0, true, true)  // local 63, next 0
                STEPO(5, xP)
                STEPE(6, xQ, xP, nb, 6, nb, 12, true, true)  // next 1, next 2
                STEPO(7, xQ)
            } else {
                // last chunk: x(512..) don't exist; stale regs only corrupt
                // h1(512) (lower lanes), which is never used
                STEPE(4, xP, xQ, rp, 42, rp, 0, true, false) // local 63
                STEPO(5, xP)
                STEPE(6, xQ, xP, rp, 0, rp, 0, false, false)
                STEPO(7, xQ)
            }
        }
    }

    // ---- epilogue: head for t = 511 (slot 7), then store final block ----
    {
        float g8  = fdpp<DPP_ROR8>(v);
        float g15 = fdpp<DPP_RMIR>(v);
        float c0 = wg[8] * g8;
        float c1 = wg[9] * fdpp<DPP_XOR1>(g8);
        c0 = fmaf(wg[10], fdpp<DPP_XOR2>(g8),  c0);
        c1 = fmaf(wg[11], fdpp<DPP_XOR3>(g8),  c1);
        c0 = fmaf(wg[12], fdpp<DPP_XOR3>(g15), c0);
        c1 = fmaf(wg[13], fdpp<DPP_XOR2>(g15), c1);
        c0 = fmaf(wg[14], fdpp<DPP_XOR1>(g15), c0);
        c1 = fmaf(wg[15], g15, c1);
        float s = c0 + c1;
        oreg = (j == 7) ? s : oreg;
        if (!up) ob[TT - 8 + j] = oreg + bo;
    }
}

extern "C" void kernel_launch(void* const* d_in, const int* in_sizes, int n_in,
                              void* d_out, int out_size, void* d_ws, size_t ws_size,
                              hipStream_t stream) {
    const float* x    = (const float*)d_in[0];
    const float* Wih0 = (const float*)d_in[1];
    const float* Whh0 = (const float*)d_in[2];
    const float* bih0 = (const float*)d_in[3];
    const float* bhh0 = (const float*)d_in[4];
    const float* Wih1 = (const float*)d_in[5];
    const float* Whh1 = (const float*)d_in[6];
    const float* bih1 = (const float*)d_in[7];
    const float* bhh1 = (const float*)d_in[8];
    const float* Wout = (const float*)d_in[9];
    const float* bout = (const float*)d_in[10];
    float* out = (float*)d_out;
    (void)d_ws; (void)ws_size; (void)in_sizes; (void)n_in; (void)out_size;

    // 4096 elements / 4 per wave = 1024 single-wave blocks -> 1 wave/SIMD
    rnn_fused<<<1024, 64, 0, stream>>>(x, Wih0, Whh0, bih0, bhh0,
                                       Wih1, Whh1, bih1, bhh1,
                                       Wout, bout, out);
}